// Round 15
// baseline (502.229 us; speedup 1.0000x reference)
//
#include <hip/hip_runtime.h>

#define TLEN 65536
#define XPLEN 65648   /* TLEN + 112 padded length */
#define TO 32769
#define OU_SIZE 50333184   /* 16*32*3*32769 */

typedef __attribute__((ext_vector_type(8))) short short8v;
typedef __attribute__((ext_vector_type(4))) float float4v;

// ---------------- helpers ----------------
__device__ __forceinline__ float fetch_xp(const float* __restrict__ xr, int idx) {
    // xp[idx] for idx in [0, XPLEN) ; xp = symmetric-pad(x, 55 left, 57 right)
    int p = idx - 55;
    p = (p < 0) ? (-1 - p) : p;
    p = (p >= TLEN) ? (2 * TLEN - 1 - p) : p;
    return xr[p];
}

__device__ __forceinline__ ushort f2bf(float f) {
    unsigned u = __float_as_uint(f);
    unsigned r = (u + 0x7fffu + ((u >> 16) & 1u)) >> 16;
    return (ushort)r;
}

// LDS-only barrier: does NOT drain vmcnt (global stores stay in flight).
__device__ __forceinline__ void bar_lds() {
    __builtin_amdgcn_sched_barrier(0);
    asm volatile("s_waitcnt lgkmcnt(0)" ::: "memory");
    __builtin_amdgcn_s_barrier();
    __builtin_amdgcn_sched_barrier(0);
}

// ---------------- K1: filters ----------------
__global__ __launch_bounds__(256) void k1_filters(
    const float* __restrict__ m, const float* __restrict__ p,
    const float* __restrict__ sd, const float* __restrict__ kb,
    float* __restrict__ Wout, ushort* __restrict__ Wtb)
{
    __shared__ float knots[32][8];
    __shared__ float yh[2][6][4];
    __shared__ float fv[2][32][112];
    __shared__ float mx[64];
    __shared__ float mv[2][7], pv[2][7];
    int tid = threadIdx.x;
    if (tid < 32) {
        float s = exp2f((float)tid * 0.125f) + sd[tid];
        float cum = 0.f;
        for (int k = 0; k < 7; ++k) {
            float c = fminf(fmaxf(kb[k] * s, 1.f), 105.f);
            knots[tid][k] = cum - 3.f * s;   // exclusive cumsum - (K//2)*scale
            cum += c;
        }
    }
    if (tid < 2) {
        float mean = 0.f;
        for (int k = 1; k <= 5; ++k) mean += m[tid * 7 + k];
        mean *= 0.2f;
        for (int k = 0; k < 7; ++k) {
            float msk = (k == 0 || k == 6) ? 0.f : 1.f;
            mv[tid][k] = (m[tid * 7 + k] - mean) * msk;
            pv[tid][k] = p[tid * 7 + k] * msk;
        }
    }
    __syncthreads();
    if (tid < 12) {
        int i = tid / 6, kk = tid % 6;
        float y0 = mv[i][kk], y1 = mv[i][kk + 1], y2 = pv[i][kk], y3 = pv[i][kk + 1];
        yh[i][kk][0] = y0;
        yh[i][kk][1] = y1;
        yh[i][kk][2] = -3.f * y0 - 2.f * y1 + 3.f * y2 - y3;
        yh[i][kk][3] = 2.f * y0 + y1 - 2.f * y2 + y3;
    }
    __syncthreads();
    for (int idx = tid; idx < 7168; idx += 256) {
        int i = idx / 3584, s = (idx / 112) % 32, fi = idx % 112;
        float xi = -56.f + (float)fi * (112.f / 111.f);
        float val = 0.f;
        for (int kk = 0; kk < 6; ++kk) {
            float x0 = knots[s][kk], x1 = knots[s][kk + 1];
            float xn = (xi - x0) / (x1 - x0);
            if (xn >= 0.f && xn < 1.f) {
                val += ((yh[i][kk][3] * xn + yh[i][kk][2]) * xn + yh[i][kk][1]) * xn + yh[i][kk][0];
            }
        }
        fv[i][s][fi] = val;
    }
    __syncthreads();
    if (tid < 64) {
        int i = tid >> 5, s = tid & 31;
        float mm_ = -1e30f;
        for (int fi = 0; fi < 112; ++fi) mm_ = fmaxf(mm_, fv[i][s][fi]);
        mx[tid] = mm_;
    }
    __syncthreads();
    for (int idx = tid; idx < 7168; idx += 256) {
        int i = idx / 3584, s = (idx / 112) % 32, fi = idx % 112;
        int o = i * 32 + s;
        Wout[fi * 64 + o] = fv[i][s][fi] / mx[o];   // layout W[k][o] (f32, for A)
    }
    for (int idx = tid; idx < 8192; idx += 256) {
        int o = idx >> 7, k = idx & 127;
        float val = (k < 112) ? fv[o >> 5][o & 31][k] / mx[o] : 0.f;
        Wtb[idx] = f2bf(val);                      // layout Wt[o][k] bf16, K padded to 128
    }
}

// ---------------- K1b: A[j][k] = sum_o W[j,o] W[k,o] ----------------
__global__ __launch_bounds__(256) void k1b_A(const float* __restrict__ W, float* __restrict__ A)
{
    int idx = blockIdx.x * 256 + threadIdx.x;
    if (idx >= 12544) return;
    int j = idx / 112, k = idx % 112;
    float s = 0.f;
    for (int o = 0; o < 64; ++o) s += W[j * 64 + o] * W[k * 64 + o];
    A[idx] = s;
}

// ---------------- K1c: C[q][dd] ----------------
__global__ __launch_bounds__(256) void k1c_C(const float* __restrict__ A, float* __restrict__ C)
{
    int idx = blockIdx.x * 256 + threadIdx.x;
    if (idx >= 448) return;
    int q = idx / 224, dd = idx % 224;
    int d = dd - 111;
    float s = 0.f;
    for (int k = q; k < 112; k += 2) {
        int jj = k + d;
        if (jj >= 0 && jj < 112) s += A[jj * 112 + k];
    }
    C[idx] = s;
}

// ---------------- K2+K3 fused: 4 compute waves + 1 dedicated flusher wave ----------------
__global__ __launch_bounds__(320) void k2k3_fused(
    const float* __restrict__ x, const ushort* __restrict__ Wtb,
    const float* __restrict__ Cg,
    float* __restrict__ out_u, float* __restrict__ out_s,
    double* __restrict__ part)
{
    __shared__ __align__(16) ushort xraw[2][384]; // bf16 window, double-buffered
    __shared__ float ub[256][33];                 // u values, 2 tile slots
    __shared__ float pb[32][65];                  // pooled values, 2 tile slots
    __shared__ __align__(16) float sx[1248];      // k3 phase: f32 x window
    __shared__ __align__(16) float Cl[448];       // k3 phase: C table
    __shared__ double wred[4];
    int row = blockIdx.y;                 // n = b*3 + c
    int b = row / 3, c = row % 3;
    const float* xr = x + row * TLEN;
    int tid = threadIdx.x;
    int l = tid & 63, w = tid >> 6;       // w==4 : flusher wave
    int lane = l;
    int r16 = l & 15, kg = l >> 4;

    union U8 { short8v v; uint u[4]; uint4 q; };

    // hoist all B-operand fragments into registers once per block (16 KB table)
    U8 wreg[4][4];
    if (w < 4) {
        const ushort* WB = Wtb + r16 * 128 + 8 * kg;
#pragma unroll
        for (int n = 0; n < 4; ++n)
#pragma unroll
            for (int ks = 0; ks < 4; ++ks)
                wreg[n][ks].q = *(const uint4*)(WB + n * 2048 + 32 * ks);
    }

    int ebase = 2 * (32 * w + r16) + 8 * kg;

    int tstart = blockIdx.x * 8;
    int tend = (blockIdx.x == 31) ? 257 : (tstart + 8);
    int ntiles = tend - tstart;

    // flush one tile (local index f): executed by wave 4 only (64 lanes)
    auto flush = [&](int f) {
        int slot = (f & 1) << 7;
        int pend_t0 = (tstart + f) * 128;
        const int NE = 128;
        // out_u: aligned float4 body (1024 items over 64 lanes)
        for (int i = lane; i < (NE << 3); i += 64) {
            int r = i & 31;
            int g = i >> 5;
            size_t gb = ((size_t)((b * 32 + r) * 3 + c)) * TO + pend_t0;
            int pad = (int)((4 - (gb & 3)) & 3);
            int e = pad + (g << 2);
            if (e + 3 < NE) {
                int t = pend_t0 + e;
                float4 v = make_float4(ub[slot + e][r], ub[slot + e + 1][r],
                                       ub[slot + e + 2][r], ub[slot + e + 3][r]);
                if (t + 3 < TO) {
                    *(float4*)(out_u + gb + e) = v;
                } else {
                    if (t     < TO) out_u[gb + e]     = v.x;
                    if (t + 1 < TO) out_u[gb + e + 1] = v.y;
                    if (t + 2 < TO) out_u[gb + e + 2] = v.z;
                    if (t + 3 < TO) out_u[gb + e + 3] = v.w;
                }
            }
        }
        // out_u: head/tail singles (4 per row when misaligned; 128 items)
        for (int i = lane; i < 128; i += 64) {
            int r = i >> 2, j = i & 3;
            size_t gb = ((size_t)((b * 32 + r) * 3 + c)) * TO + pend_t0;
            int pad = (int)((4 - (gb & 3)) & 3);
            if (pad > 0) {
                int G4 = ((NE - pad) >> 2) << 2;
                int e = (j < pad) ? j : (pad + G4 + (j - pad));
                if (e < NE) {
                    int t = pend_t0 + e;
                    if (t < TO) out_u[gb + e] = ub[slot + e][r];
                }
            }
        }
        // out_s: aligned float4 (256 items)
        int ps = (f & 1) << 5;
        int tp0 = pend_t0 >> 2;
        for (int i = lane; i < 256; i += 64) {
            int r = i & 31;
            int g = i >> 5;   // 0..7
            int tp = g << 2;
            size_t sb = ((size_t)(row * 32 + r)) * 8192 + tp0;
            if (tp0 + tp + 3 < 8192) {
                float4 v = make_float4(pb[r][ps + tp], pb[r][ps + tp + 1],
                                       pb[r][ps + tp + 2], pb[r][ps + tp + 3]);
                *(float4*)(out_s + sb + tp) = v;
            } else {
#pragma unroll
                for (int j = 0; j < 4; ++j)
                    if (tp0 + tp + j < 8192) out_s[sb + tp + j] = pb[r][ps + tp + j];
            }
        }
    };

    // prologue: stage tile 0 (compute waves only; tid<256)
    if (w < 4) {
        int i0 = 2 * tstart * 128 + tid;
        float v0 = (i0 < XPLEN) ? fetch_xp(xr, i0) : 0.f;
        float v1 = 0.f;
        if (tid < 128) {
            int i1 = i0 + 256;
            v1 = (i1 < XPLEN) ? fetch_xp(xr, i1) : 0.f;
        }
        xraw[0][tid] = f2bf(v0);
        if (tid < 128) xraw[0][tid + 256] = f2bf(v1);
    }
    bar_lds();

    for (int it = 0; it < ntiles; ++it) {
        int half = it & 1;
        bool hn = (it + 1 < ntiles);
        float n0 = 0.f, n1 = 0.f;
        if (w < 4) {
            // compute waves: issue next tile's loads (their vmcnt is loads-only now)
            if (hn) {
                int i0 = 2 * (tstart + it + 1) * 128 + tid;
                n0 = (i0 < XPLEN) ? fetch_xp(xr, i0) : 0.f;
                if (tid < 128) {
                    int i1 = i0 + 256;
                    n1 = (i1 < XPLEN) ? fetch_xp(xr, i1) : 0.f;
                }
            }
        } else {
            // flusher wave: store previous tile while compute waves stage/compute
            if (it >= 1) flush(it - 1);
        }
        __builtin_amdgcn_sched_barrier(0);
        if (w < 4 && hn) {
            xraw[(it + 1) & 1][tid] = f2bf(n0);
            if (tid < 128) xraw[(it + 1) & 1][tid + 256] = f2bf(n1);
        }
        bar_lds();

        if (w < 4) {
            // compute tile it
            const ushort* xcur = xraw[half];
            float4v acc[2][4];
#pragma unroll
            for (int mt = 0; mt < 2; ++mt)
#pragma unroll
                for (int n = 0; n < 4; ++n)
                    acc[mt][n] = (float4v){0.f, 0.f, 0.f, 0.f};

#pragma unroll
            for (int ks = 0; ks < 4; ++ks) {
                U8 a0, a1;
                int e0 = ebase + 32 * ks;
#pragma unroll
                for (int q = 0; q < 4; ++q) {
                    a0.u[q] = *(const uint*)&xcur[e0 + 2 * q];        // t .. t+15
                    a1.u[q] = *(const uint*)&xcur[e0 + 32 + 2 * q];   // t+16 ..
                }
#pragma unroll
                for (int n = 0; n < 4; ++n) {
                    acc[0][n] = __builtin_amdgcn_mfma_f32_16x16x32_bf16(a0.v, wreg[n][ks].v, acc[0][n], 0, 0, 0);
                    acc[1][n] = __builtin_amdgcn_mfma_f32_16x16x32_bf16(a1.v, wreg[n][ks].v, acc[1][n], 0, 0, 0);
                }
            }

            // modulus + pool into this tile's LDS slot
            int t0 = (tstart + it) * 128;
#pragma unroll
            for (int mt = 0; mt < 2; ++mt) {
                int tl = 32 * w + 16 * mt + 4 * kg;
                int ts = t0 + tl;
                float u1[4], u2[4];
#pragma unroll
                for (int r = 0; r < 4; ++r) {
                    float re1 = acc[mt][0][r], im1 = acc[mt][2][r];
                    float re2 = acc[mt][1][r], im2 = acc[mt][3][r];
                    u1[r] = sqrtf(re1 * re1 + im1 * im1);
                    u2[r] = sqrtf(re2 * re2 + im2 * im2);
                }
#pragma unroll
                for (int r = 0; r < 4; ++r) {
                    ub[(half << 7) + tl + r][r16]      = u1[r];
                    ub[(half << 7) + tl + r][r16 + 16] = u2[r];
                }
                if (ts + 3 < TO) {
                    int pc = (half << 5) + (tl >> 2);
                    pb[r16][pc]      = (u1[0] + u1[1] + u1[2] + u1[3]) * 0.25f;
                    pb[r16 + 16][pc] = (u2[0] + u2[1] + u2[2] + u2[3]) * 0.25f;
                }
            }
        }
        bar_lds();
    }
    // epilogue: flush final tile (stores drain under the k3 phase below)
    if (w == 4) flush(ntiles - 1);

    // ---------------- k3 phase: interior inverse + loss for 2 chunks ----------------
    for (int li = tid; li < 448; li += 320) Cl[li] = Cg[li];
    for (int cc = 0; cc < 2; ++cc) {
        int chunk = 2 * blockIdx.x + cc;
        int s0 = 56 + chunk * 1024;
        if (cc) bar_lds();              // protect sx reuse from previous chunk's readers
        for (int li = tid; li < 1248; li += 320) {
            int pp = s0 - 111 + li;
            pp = (pp < 0) ? (-1 - pp) : pp;
            pp = (pp >= TLEN) ? (2 * TLEN - 1 - pp) : pp;
            sx[li] = xr[pp];
        }
        bar_lds();

        if (w < 4) {
            const float* Ce = Cl + 224;   // qe = (55+s0)&1 == 1 always (s0 even)
            const float* Co = Cl;
            int base = tid * 4;
            float a0 = 0.f, a1 = 0.f, a2 = 0.f, a3 = 0.f;
            float4 cur = *(const float4*)&sx[base];
#pragma unroll 4
            for (int d4 = 0; d4 < 56; ++d4) {
                float4 nxt = *(const float4*)&sx[base + 4 * d4 + 4];
                float4 cev = *(const float4*)&Ce[4 * d4];     // LDS broadcast
                float4 cov = *(const float4*)&Co[4 * d4];     // LDS broadcast
                a0 = fmaf(cur.x, cev.x, a0); a1 = fmaf(cur.y, cov.x, a1); a2 = fmaf(cur.z, cev.x, a2); a3 = fmaf(cur.w, cov.x, a3);
                a0 = fmaf(cur.y, cev.y, a0); a1 = fmaf(cur.z, cov.y, a1); a2 = fmaf(cur.w, cev.y, a2); a3 = fmaf(nxt.x, cov.y, a3);
                a0 = fmaf(cur.z, cev.z, a0); a1 = fmaf(cur.w, cov.z, a1); a2 = fmaf(nxt.x, cev.z, a2); a3 = fmaf(nxt.y, cov.z, a3);
                a0 = fmaf(cur.w, cev.w, a0); a1 = fmaf(nxt.x, cov.w, a1); a2 = fmaf(nxt.y, cev.w, a2); a3 = fmaf(nxt.z, cov.w, a3);
                cur = nxt;
            }

            int sb = s0 + base;
            double lsum = 0.0;
            if (sb + 0 <= 65478) { float d = a0 - sx[base + 111]; lsum += (double)d * d; }
            if (sb + 1 <= 65478) { float d = a1 - sx[base + 112]; lsum += (double)d * d; }
            if (sb + 2 <= 65478) { float d = a2 - sx[base + 113]; lsum += (double)d * d; }
            if (sb + 3 <= 65478) { float d = a3 - sx[base + 114]; lsum += (double)d * d; }
            for (int off = 32; off > 0; off >>= 1) lsum += __shfl_down(lsum, off, 64);
            if ((tid & 63) == 0) wred[w] = lsum;
        }
        bar_lds();
        if (tid == 0)
            part[row * 64 + chunk] = wred[0] + wred[1] + wred[2] + wred[3];
    }
}

// ---------------- K4: edge g_xp evals + edge loss partials (no atomics) ----------------
__global__ __launch_bounds__(256) void k4_edge(
    const float* __restrict__ x, const float* __restrict__ A,
    double* __restrict__ part2)
{
    __shared__ float Al[112][113];
    __shared__ float xpw[240];
    __shared__ double wacc[4];
    int row = blockIdx.x >> 1;
    int side = blockIdx.x & 1;
    const float* xr = x + row * TLEN;
    int tid = threadIdx.x;

    for (int idx = tid; idx < 12544; idx += 256)
        Al[idx / 112][idx % 112] = A[idx];
    {
        int n_x = side ? 225 : 222;
        int woff0 = side ? 65423 : 0;
        if (tid < n_x) xpw[tid] = fetch_xp(xr, woff0 + tid);
    }
    __syncthreads();

    int w = tid >> 6, lane = tid & 63;
    int nS = side ? 57 : 56;
    int woff = side ? 65423 : 0;
    double lacc = 0.0;
    for (int s = w; s < nS; s += 4) {
        float part = 0.f;
#pragma unroll
        for (int half = 0; half < 2; ++half) {
            int i;
            bool has;
            if (!side) { i = half ? (54 - s) : (55 + s); has = half ? (s <= 54) : true; }
            else       { i = half ? (65647 - s) : (65534 + s); has = true; }
            if (has) {
                int klo = max(0, i - 65536);
                int khi = min(111, i);
                int k0 = klo + ((klo ^ i) & 1);
                for (int k = k0; k <= khi; k += 2) {
                    int bi = i - k - woff;
                    part = fmaf(xpw[bi + lane], Al[lane][k], part);
                    if (lane < 48)
                        part = fmaf(xpw[bi + 64 + lane], Al[lane + 64][k], part);
                }
            }
        }
        for (int off = 32; off > 0; off >>= 1) part += __shfl_down(part, off, 64);
        if (lane == 0) {
            float xs = xpw[side ? (111 + s) : (s + 55)];
            float diff = part - xs;
            lacc += (double)diff * diff;
        }
    }
    if (lane == 0) wacc[w] = lacc;
    __syncthreads();
    if (tid == 0) part2[blockIdx.x] = wacc[0] + wacc[1] + wacc[2] + wacc[3];
}

// ---------------- K5: final reduction ----------------
__global__ __launch_bounds__(256) void k5_final(
    const double* __restrict__ part, const double* __restrict__ part2,
    float* __restrict__ out_loss)
{
    __shared__ double red[256];
    double acc = 0.0;
    for (int idx = threadIdx.x; idx < 3072; idx += 256) acc += part[idx];
    if (threadIdx.x < 96) acc += part2[threadIdx.x];
    red[threadIdx.x] = acc;
    __syncthreads();
    for (int st = 128; st > 0; st >>= 1) {
        if (threadIdx.x < st) red[threadIdx.x] += red[threadIdx.x + st];
        __syncthreads();
    }
    if (threadIdx.x == 0)
        out_loss[0] = (float)(red[0] / 3145728.0);
}

// ---------------- launch ----------------
extern "C" void kernel_launch(void* const* d_in, const int* in_sizes, int n_in,
                              void* d_out, int out_size, void* d_ws, size_t ws_size,
                              hipStream_t stream)
{
    (void)in_sizes; (void)n_in; (void)ws_size;
    const float* x  = (const float*)d_in[0];
    const float* m  = (const float*)d_in[1];
    const float* p  = (const float*)d_in[2];
    const float* sd = (const float*)d_in[3];
    const float* kb = (const float*)d_in[4];
    float* out = (float*)d_out;
    float* ws  = (float*)d_ws;

    float* ws_w     = ws;            // 7168 : W[k][o] f32
    float* ws_C     = ws + 7168;     // 448  : C[q][224]
    float* ws_A     = ws + 7616;     // 12544: A[j][k] -> ends 20160
    double* ws_part  = (double*)(ws + 20160); // 3072 doubles -> ends 26304
    double* ws_part2 = (double*)(ws + 26304); // 96 doubles   -> ends 26496
    ushort* ws_wtb  = (ushort*)(ws + 26496);  // 8192 ushort: Wt[o][k] bf16 padded

    k1_filters<<<1, 256, 0, stream>>>(m, p, sd, kb, ws_w, ws_wtb);
    k1b_A<<<49, 256, 0, stream>>>(ws_w, ws_A);
    k1c_C<<<2, 256, 0, stream>>>(ws_A, ws_C);
    k2k3_fused<<<dim3(32, 48), 320, 0, stream>>>(x, ws_wtb, ws_C, out, out + OU_SIZE, ws_part);
    k4_edge<<<96, 256, 0, stream>>>(x, ws_A, ws_part2);
    k5_final<<<1, 256, 0, stream>>>(ws_part, ws_part2, out + (out_size - 1));
}

// Round 16
// 247.813 us; speedup vs baseline: 2.0266x; 2.0266x over previous
//
#include <hip/hip_runtime.h>

#define TLEN 65536
#define XPLEN 65648   /* TLEN + 112 padded length */
#define TO 32769
#define OU_SIZE 50333184   /* 16*32*3*32769 */

typedef __attribute__((ext_vector_type(8))) short short8v;
typedef __attribute__((ext_vector_type(4))) float float4v;

// ---------------- helpers ----------------
__device__ __forceinline__ float fetch_xp(const float* __restrict__ xr, int idx) {
    // xp[idx] for idx in [0, XPLEN) ; xp = symmetric-pad(x, 55 left, 57 right)
    int p = idx - 55;
    p = (p < 0) ? (-1 - p) : p;
    p = (p >= TLEN) ? (2 * TLEN - 1 - p) : p;
    return xr[p];
}

__device__ __forceinline__ ushort f2bf(float f) {
    unsigned u = __float_as_uint(f);
    unsigned r = (u + 0x7fffu + ((u >> 16) & 1u)) >> 16;
    return (ushort)r;
}

// LDS-only barrier: does NOT drain vmcnt (global stores stay in flight).
__device__ __forceinline__ void bar_lds() {
    __builtin_amdgcn_sched_barrier(0);
    asm volatile("s_waitcnt lgkmcnt(0)" ::: "memory");
    __builtin_amdgcn_s_barrier();
    __builtin_amdgcn_sched_barrier(0);
}

// ---------------- K1: filters ----------------
__global__ __launch_bounds__(256) void k1_filters(
    const float* __restrict__ m, const float* __restrict__ p,
    const float* __restrict__ sd, const float* __restrict__ kb,
    float* __restrict__ Wout, ushort* __restrict__ Wtb)
{
    __shared__ float knots[32][8];
    __shared__ float yh[2][6][4];
    __shared__ float fv[2][32][112];
    __shared__ float mx[64];
    __shared__ float mv[2][7], pv[2][7];
    int tid = threadIdx.x;
    if (tid < 32) {
        float s = exp2f((float)tid * 0.125f) + sd[tid];
        float cum = 0.f;
        for (int k = 0; k < 7; ++k) {
            float c = fminf(fmaxf(kb[k] * s, 1.f), 105.f);
            knots[tid][k] = cum - 3.f * s;   // exclusive cumsum - (K//2)*scale
            cum += c;
        }
    }
    if (tid < 2) {
        float mean = 0.f;
        for (int k = 1; k <= 5; ++k) mean += m[tid * 7 + k];
        mean *= 0.2f;
        for (int k = 0; k < 7; ++k) {
            float msk = (k == 0 || k == 6) ? 0.f : 1.f;
            mv[tid][k] = (m[tid * 7 + k] - mean) * msk;
            pv[tid][k] = p[tid * 7 + k] * msk;
        }
    }
    __syncthreads();
    if (tid < 12) {
        int i = tid / 6, kk = tid % 6;
        float y0 = mv[i][kk], y1 = mv[i][kk + 1], y2 = pv[i][kk], y3 = pv[i][kk + 1];
        yh[i][kk][0] = y0;
        yh[i][kk][1] = y1;
        yh[i][kk][2] = -3.f * y0 - 2.f * y1 + 3.f * y2 - y3;
        yh[i][kk][3] = 2.f * y0 + y1 - 2.f * y2 + y3;
    }
    __syncthreads();
    for (int idx = tid; idx < 7168; idx += 256) {
        int i = idx / 3584, s = (idx / 112) % 32, fi = idx % 112;
        float xi = -56.f + (float)fi * (112.f / 111.f);
        float val = 0.f;
        for (int kk = 0; kk < 6; ++kk) {
            float x0 = knots[s][kk], x1 = knots[s][kk + 1];
            float xn = (xi - x0) / (x1 - x0);
            if (xn >= 0.f && xn < 1.f) {
                val += ((yh[i][kk][3] * xn + yh[i][kk][2]) * xn + yh[i][kk][1]) * xn + yh[i][kk][0];
            }
        }
        fv[i][s][fi] = val;
    }
    __syncthreads();
    if (tid < 64) {
        int i = tid >> 5, s = tid & 31;
        float mm_ = -1e30f;
        for (int fi = 0; fi < 112; ++fi) mm_ = fmaxf(mm_, fv[i][s][fi]);
        mx[tid] = mm_;
    }
    __syncthreads();
    for (int idx = tid; idx < 7168; idx += 256) {
        int i = idx / 3584, s = (idx / 112) % 32, fi = idx % 112;
        int o = i * 32 + s;
        Wout[fi * 64 + o] = fv[i][s][fi] / mx[o];   // layout W[k][o] (f32, for A)
    }
    for (int idx = tid; idx < 8192; idx += 256) {
        int o = idx >> 7, k = idx & 127;
        float val = (k < 112) ? fv[o >> 5][o & 31][k] / mx[o] : 0.f;
        Wtb[idx] = f2bf(val);                      // layout Wt[o][k] bf16, K padded to 128
    }
}

// ---------------- K1b: A[j][k] = sum_o W[j,o] W[k,o] ----------------
__global__ __launch_bounds__(256) void k1b_A(const float* __restrict__ W, float* __restrict__ A)
{
    int idx = blockIdx.x * 256 + threadIdx.x;
    if (idx >= 12544) return;
    int j = idx / 112, k = idx % 112;
    float s = 0.f;
    for (int o = 0; o < 64; ++o) s += W[j * 64 + o] * W[k * 64 + o];
    A[idx] = s;
}

// ---------------- K1c: C[q][dd] ----------------
__global__ __launch_bounds__(256) void k1c_C(const float* __restrict__ A, float* __restrict__ C)
{
    int idx = blockIdx.x * 256 + threadIdx.x;
    if (idx >= 448) return;
    int q = idx / 224, dd = idx % 224;
    int d = dd - 111;
    float s = 0.f;
    for (int k = q; k < 112; k += 2) {
        int jj = k + d;
        if (jj >= 0 && jj < 112) s += A[jj * 112 + k];
    }
    C[idx] = s;
}

// ---------------- K2+K3 fused: MFMA conv + modulus/pool + interior inverse loss ----------------
__global__ __launch_bounds__(256) void k2k3_fused(
    const float* __restrict__ x, const ushort* __restrict__ Wtb,
    const float* __restrict__ Cg,
    float* __restrict__ out_u, float* __restrict__ out_s,
    double* __restrict__ part)
{
    __shared__ __align__(16) ushort xraw[2][384]; // bf16 window, double-buffered
    __shared__ float ub[256][33];                 // u values, 2 tile slots
    __shared__ float pb[32][65];                  // pooled values, 2 tile slots
    __shared__ __align__(16) float sx[1248];      // k3 phase: f32 x window
    __shared__ __align__(16) float Cl[448];       // k3 phase: C table
    __shared__ double wred[4];
    int row = blockIdx.y;                 // n = b*3 + c
    int b = row / 3, c = row % 3;
    const float* xr = x + row * TLEN;
    int tid = threadIdx.x;
    int l = tid & 63, w = tid >> 6;
    int r16 = l & 15, kg = l >> 4;

    union U8 { short8v v; uint u[4]; uint4 q; };

    // hoist all B-operand fragments into registers once per block (16 KB table)
    const ushort* WB = Wtb + r16 * 128 + 8 * kg;
    U8 wreg[4][4];
#pragma unroll
    for (int n = 0; n < 4; ++n)
#pragma unroll
        for (int ks = 0; ks < 4; ++ks)
            wreg[n][ks].q = *(const uint4*)(WB + n * 2048 + 32 * ks);

    int ebase = 2 * (32 * w + r16) + 8 * kg;

    int tstart = blockIdx.x * 8;
    int tend = (blockIdx.x == 31) ? 257 : (tstart + 8);
    int ntiles = tend - tstart;

    // flush one tile (local index f): 512 B sequential per output row
    auto flush = [&](int f) {
        int slot = (f & 1) << 7;
        int pend_t0 = (tstart + f) * 128;
        const int NE = 128;
        // out_u: aligned float4 body
        for (int i = tid; i < (NE << 3); i += 256) {
            int r = i & 31;
            int g = i >> 5;
            size_t gb = ((size_t)((b * 32 + r) * 3 + c)) * TO + pend_t0;
            int pad = (int)((4 - (gb & 3)) & 3);
            int e = pad + (g << 2);
            if (e + 3 < NE) {
                int t = pend_t0 + e;
                float4 v = make_float4(ub[slot + e][r], ub[slot + e + 1][r],
                                       ub[slot + e + 2][r], ub[slot + e + 3][r]);
                if (t + 3 < TO) {
                    *(float4*)(out_u + gb + e) = v;
                } else {
                    if (t     < TO) out_u[gb + e]     = v.x;
                    if (t + 1 < TO) out_u[gb + e + 1] = v.y;
                    if (t + 2 < TO) out_u[gb + e + 2] = v.z;
                    if (t + 3 < TO) out_u[gb + e + 3] = v.w;
                }
            }
        }
        // out_u: head/tail singles (4 per row when misaligned)
        if (tid < 128) {
            int r = tid >> 2, j = tid & 3;
            size_t gb = ((size_t)((b * 32 + r) * 3 + c)) * TO + pend_t0;
            int pad = (int)((4 - (gb & 3)) & 3);
            if (pad > 0) {
                int G4 = ((NE - pad) >> 2) << 2;
                int e = (j < pad) ? j : (pad + G4 + (j - pad));
                if (e < NE) {
                    int t = pend_t0 + e;
                    if (t < TO) out_u[gb + e] = ub[slot + e][r];
                }
            }
        }
        // out_s: aligned float4 (32 pooled values per row per tile)
        int ps = (f & 1) << 5;
        int tp0 = pend_t0 >> 2;
        {
            int r = tid & 31;
            int g = tid >> 5;   // 0..7
            int tp = g << 2;
            size_t sb = ((size_t)(row * 32 + r)) * 8192 + tp0;
            if (tp0 + tp + 3 < 8192) {
                float4 v = make_float4(pb[r][ps + tp], pb[r][ps + tp + 1],
                                       pb[r][ps + tp + 2], pb[r][ps + tp + 3]);
                *(float4*)(out_s + sb + tp) = v;
            } else {
#pragma unroll
                for (int j = 0; j < 4; ++j)
                    if (tp0 + tp + j < 8192) out_s[sb + tp + j] = pb[r][ps + tp + j];
            }
        }
    };

    // prologue: stage tile 0
    {
        int i0 = 2 * tstart * 128 + tid;
        float v0 = (i0 < XPLEN) ? fetch_xp(xr, i0) : 0.f;
        float v1 = 0.f;
        if (tid < 128) {
            int i1 = i0 + 256;
            v1 = (i1 < XPLEN) ? fetch_xp(xr, i1) : 0.f;
        }
        xraw[0][tid] = f2bf(v0);
        if (tid < 128) xraw[0][tid + 256] = f2bf(v1);
    }
    bar_lds();

    for (int it = 0; it < ntiles; ++it) {
        int half = it & 1;
        // 1) issue next tile's global loads FIRST (older than flush stores -> counted vmcnt)
        float n0 = 0.f, n1 = 0.f;
        bool hn = (it + 1 < ntiles);
        if (hn) {
            int i0 = 2 * (tstart + it + 1) * 128 + tid;
            n0 = (i0 < XPLEN) ? fetch_xp(xr, i0) : 0.f;
            if (tid < 128) {
                int i1 = i0 + 256;
                n1 = (i1 < XPLEN) ? fetch_xp(xr, i1) : 0.f;
            }
        }
        __builtin_amdgcn_sched_barrier(0);
        // 2) flush previous tile's results (stores stay in flight; never drained)
        if (it >= 1) flush(it - 1);
        __builtin_amdgcn_sched_barrier(0);
        // 3) write staged registers to LDS (waits counted vmcnt for loads only)
        if (hn) {
            xraw[(it + 1) & 1][tid] = f2bf(n0);
            if (tid < 128) xraw[(it + 1) & 1][tid + 256] = f2bf(n1);
        }
        bar_lds();

        // 4) compute tile it
        const ushort* xcur = xraw[half];
        float4v acc[2][4];
#pragma unroll
        for (int mt = 0; mt < 2; ++mt)
#pragma unroll
            for (int n = 0; n < 4; ++n)
                acc[mt][n] = (float4v){0.f, 0.f, 0.f, 0.f};

#pragma unroll
        for (int ks = 0; ks < 4; ++ks) {
            U8 a0, a1;
            int e0 = ebase + 32 * ks;
#pragma unroll
            for (int q = 0; q < 4; ++q) {
                a0.u[q] = *(const uint*)&xcur[e0 + 2 * q];        // t .. t+15
                a1.u[q] = *(const uint*)&xcur[e0 + 32 + 2 * q];   // t+16 ..
            }
#pragma unroll
            for (int n = 0; n < 4; ++n) {
                acc[0][n] = __builtin_amdgcn_mfma_f32_16x16x32_bf16(a0.v, wreg[n][ks].v, acc[0][n], 0, 0, 0);
                acc[1][n] = __builtin_amdgcn_mfma_f32_16x16x32_bf16(a1.v, wreg[n][ks].v, acc[1][n], 0, 0, 0);
            }
        }

        // modulus + pool into this tile's LDS slot
        int t0 = (tstart + it) * 128;
#pragma unroll
        for (int mt = 0; mt < 2; ++mt) {
            int tl = 32 * w + 16 * mt + 4 * kg;
            int ts = t0 + tl;
            float u1[4], u2[4];
#pragma unroll
            for (int r = 0; r < 4; ++r) {
                float re1 = acc[mt][0][r], im1 = acc[mt][2][r];
                float re2 = acc[mt][1][r], im2 = acc[mt][3][r];
                u1[r] = sqrtf(re1 * re1 + im1 * im1);
                u2[r] = sqrtf(re2 * re2 + im2 * im2);
            }
#pragma unroll
            for (int r = 0; r < 4; ++r) {
                ub[(half << 7) + tl + r][r16]      = u1[r];
                ub[(half << 7) + tl + r][r16 + 16] = u2[r];
            }
            if (ts + 3 < TO) {
                int pc = (half << 5) + (tl >> 2);
                pb[r16][pc]      = (u1[0] + u1[1] + u1[2] + u1[3]) * 0.25f;
                pb[r16 + 16][pc] = (u2[0] + u2[1] + u2[2] + u2[3]) * 0.25f;
            }
        }
        bar_lds();
    }
    // epilogue: flush final tile (stores drain under the k3 phase below)
    flush(ntiles - 1);

    // ---------------- k3 phase: interior inverse + loss for 2 chunks ----------------
    for (int li = tid; li < 448; li += 256) Cl[li] = Cg[li];
    for (int cc = 0; cc < 2; ++cc) {
        int chunk = 2 * blockIdx.x + cc;
        int s0 = 56 + chunk * 1024;
        if (cc) bar_lds();              // protect sx reuse from previous chunk's readers
        for (int li = tid; li < 1248; li += 256) {
            int pp = s0 - 111 + li;
            pp = (pp < 0) ? (-1 - pp) : pp;
            pp = (pp >= TLEN) ? (2 * TLEN - 1 - pp) : pp;
            sx[li] = xr[pp];
        }
        bar_lds();

        int qe = (55 + s0) & 1;
        const float* Ce = Cl + qe * 224;
        const float* Co = Cl + (qe ^ 1) * 224;
        int base = tid * 4;
        float a0 = 0.f, a1 = 0.f, a2 = 0.f, a3 = 0.f;
        float4 cur = *(const float4*)&sx[base];
#pragma unroll 4
        for (int d4 = 0; d4 < 56; ++d4) {
            float4 nxt = *(const float4*)&sx[base + 4 * d4 + 4];
            float4 cev = *(const float4*)&Ce[4 * d4];     // LDS broadcast
            float4 cov = *(const float4*)&Co[4 * d4];     // LDS broadcast
            a0 = fmaf(cur.x, cev.x, a0); a1 = fmaf(cur.y, cov.x, a1); a2 = fmaf(cur.z, cev.x, a2); a3 = fmaf(cur.w, cov.x, a3);
            a0 = fmaf(cur.y, cev.y, a0); a1 = fmaf(cur.z, cov.y, a1); a2 = fmaf(cur.w, cev.y, a2); a3 = fmaf(nxt.x, cov.y, a3);
            a0 = fmaf(cur.z, cev.z, a0); a1 = fmaf(cur.w, cov.z, a1); a2 = fmaf(nxt.x, cev.z, a2); a3 = fmaf(nxt.y, cov.z, a3);
            a0 = fmaf(cur.w, cev.w, a0); a1 = fmaf(nxt.x, cov.w, a1); a2 = fmaf(nxt.y, cov.w, a2); a3 = fmaf(nxt.z, cov.w, a3);
            cur = nxt;
        }

        int sb = s0 + base;
        double lsum = 0.0;
        if (sb + 0 <= 65478) { float d = a0 - sx[base + 111]; lsum += (double)d * d; }
        if (sb + 1 <= 65478) { float d = a1 - sx[base + 112]; lsum += (double)d * d; }
        if (sb + 2 <= 65478) { float d = a2 - sx[base + 113]; lsum += (double)d * d; }
        if (sb + 3 <= 65478) { float d = a3 - sx[base + 114]; lsum += (double)d * d; }
        for (int off = 32; off > 0; off >>= 1) lsum += __shfl_down(lsum, off, 64);
        if ((tid & 63) == 0) wred[w] = lsum;
        bar_lds();
        if (tid == 0)
            part[row * 64 + chunk] = wred[0] + wred[1] + wred[2] + wred[3];
    }
}

// ---------------- K4: edge g_xp evals + edge loss partials (no atomics) ----------------
__global__ __launch_bounds__(256) void k4_edge(
    const float* __restrict__ x, const float* __restrict__ A,
    double* __restrict__ part2)
{
    __shared__ float Al[112][113];
    __shared__ float xpw[240];
    __shared__ double wacc[4];
    int row = blockIdx.x >> 1;
    int side = blockIdx.x & 1;
    const float* xr = x + row * TLEN;
    int tid = threadIdx.x;

    for (int idx = tid; idx < 12544; idx += 256)
        Al[idx / 112][idx % 112] = A[idx];
    {
        int n_x = side ? 225 : 222;
        int woff0 = side ? 65423 : 0;
        if (tid < n_x) xpw[tid] = fetch_xp(xr, woff0 + tid);
    }
    __syncthreads();

    int w = tid >> 6, lane = tid & 63;
    int nS = side ? 57 : 56;
    int woff = side ? 65423 : 0;
    double lacc = 0.0;
    for (int s = w; s < nS; s += 4) {
        float part = 0.f;
#pragma unroll
        for (int half = 0; half < 2; ++half) {
            int i;
            bool has;
            if (!side) { i = half ? (54 - s) : (55 + s); has = half ? (s <= 54) : true; }
            else       { i = half ? (65647 - s) : (65534 + s); has = true; }
            if (has) {
                int klo = max(0, i - 65536);
                int khi = min(111, i);
                int k0 = klo + ((klo ^ i) & 1);
                for (int k = k0; k <= khi; k += 2) {
                    int bi = i - k - woff;
                    part = fmaf(xpw[bi + lane], Al[lane][k], part);
                    if (lane < 48)
                        part = fmaf(xpw[bi + 64 + lane], Al[lane + 64][k], part);
                }
            }
        }
        for (int off = 32; off > 0; off >>= 1) part += __shfl_down(part, off, 64);
        if (lane == 0) {
            float xs = xpw[side ? (111 + s) : (s + 55)];
            float diff = part - xs;
            lacc += (double)diff * diff;
        }
    }
    if (lane == 0) wacc[w] = lacc;
    __syncthreads();
    if (tid == 0) part2[blockIdx.x] = wacc[0] + wacc[1] + wacc[2] + wacc[3];
}

// ---------------- K5: final reduction ----------------
__global__ __launch_bounds__(256) void k5_final(
    const double* __restrict__ part, const double* __restrict__ part2,
    float* __restrict__ out_loss)
{
    __shared__ double red[256];
    double acc = 0.0;
    for (int idx = threadIdx.x; idx < 3072; idx += 256) acc += part[idx];
    if (threadIdx.x < 96) acc += part2[threadIdx.x];
    red[threadIdx.x] = acc;
    __syncthreads();
    for (int st = 128; st > 0; st >>= 1) {
        if (threadIdx.x < st) red[threadIdx.x] += red[threadIdx.x + st];
        __syncthreads();
    }
    if (threadIdx.x == 0)
        out_loss[0] = (float)(red[0] / 3145728.0);
}

// ---------------- launch ----------------
extern "C" void kernel_launch(void* const* d_in, const int* in_sizes, int n_in,
                              void* d_out, int out_size, void* d_ws, size_t ws_size,
                              hipStream_t stream)
{
    (void)in_sizes; (void)n_in; (void)ws_size;
    const float* x  = (const float*)d_in[0];
    const float* m  = (const float*)d_in[1];
    const float* p  = (const float*)d_in[2];
    const float* sd = (const float*)d_in[3];
    const float* kb = (const float*)d_in[4];
    float* out = (float*)d_out;
    float* ws  = (float*)d_ws;

    float* ws_w     = ws;            // 7168 : W[k][o] f32
    float* ws_C     = ws + 7168;     // 448  : C[q][224]
    float* ws_A     = ws + 7616;     // 12544: A[j][k] -> ends 20160
    double* ws_part  = (double*)(ws + 20160); // 3072 doubles -> ends 26304
    double* ws_part2 = (double*)(ws + 26304); // 96 doubles   -> ends 26496
    ushort* ws_wtb  = (ushort*)(ws + 26496);  // 8192 ushort: Wt[o][k] bf16 padded

    k1_filters<<<1, 256, 0, stream>>>(m, p, sd, kb, ws_w, ws_wtb);
    k1b_A<<<49, 256, 0, stream>>>(ws_w, ws_A);
    k1c_C<<<2, 256, 0, stream>>>(ws_A, ws_C);
    k2k3_fused<<<dim3(32, 48), 256, 0, stream>>>(x, ws_wtb, ws_C, out, out + OU_SIZE, ws_part);
    k4_edge<<<96, 256, 0, stream>>>(x, ws_A, ws_part2);
    k5_final<<<1, 256, 0, stream>>>(ws_part, ws_part2, out + (out_size - 1));
}